// Round 4
// baseline (658.673 us; speedup 1.0000x reference)
//
#include <hip/hip_runtime.h>
#include <stdint.h>

#define B_ROWS 8192
#define K_DIM 2048
#define N_DIM 2048
#define NPOP 8

typedef float f32x4 __attribute__((ext_vector_type(4)));
typedef __bf16 bf16x8 __attribute__((ext_vector_type(8)));

__device__ __forceinline__ unsigned short f2bf(float f) {
  unsigned int u = __float_as_uint(f);
  u += 0x7fffu + ((u >> 16) & 1u);   // round-to-nearest-even
  return (unsigned short)(u >> 16);
}

// async global->LDS, 16B per lane; LDS side = wave-uniform base + lane*16
__device__ __forceinline__ void glds16(const unsigned short* g, unsigned short* l) {
  __builtin_amdgcn_global_load_lds(
      (__attribute__((address_space(1))) unsigned int*)g,
      (__attribute__((address_space(3))) unsigned int*)l, 16, 0, 0);
}

// ---- W fp32 -> bf16 ----
__global__ void prep_w_kernel(const float* __restrict__ W, unsigned short* __restrict__ Wb) {
  const int n4 = NPOP * N_DIM * K_DIM / 4;
  int stride = gridDim.x * blockDim.x;
  for (int i = blockIdx.x * blockDim.x + threadIdx.x; i < n4; i += stride) {
    float4 v = reinterpret_cast<const float4*>(W)[i];
    ushort4 s;
    s.x = f2bf(v.x); s.y = f2bf(v.y); s.z = f2bf(v.z); s.w = f2bf(v.w);
    reinterpret_cast<ushort4*>(Wb)[i] = s;
  }
}

// ---- selector logits, top-2 -> sel[row]; also zero-init out ----
__global__ void prep_x_sel_kernel(const float* __restrict__ x,
                                  const float* __restrict__ Ws,
                                  const float* __restrict__ bs,
                                  int* __restrict__ sel,
                                  float* __restrict__ out) {
  // zero-init output (gemm accumulates atomically into it)
  {
    float4 z4 = {0.f, 0.f, 0.f, 0.f};
    float4* o4 = reinterpret_cast<float4*>(out);
    const int n4 = B_ROWS * N_DIM / 4;
    int stride = gridDim.x * blockDim.x;
    for (int i = blockIdx.x * blockDim.x + threadIdx.x; i < n4; i += stride) o4[i] = z4;
  }

  const int w = threadIdx.x >> 6;
  const int l = threadIdx.x & 63;
  const int r = blockIdx.x * 4 + w;   // 2048 blocks * 4 waves = 8192 rows

  float acc[NPOP];
#pragma unroll
  for (int p = 0; p < NPOP; ++p) acc[p] = 0.f;

  const float4* x4  = reinterpret_cast<const float4*>(x);
  const float4* Ws4 = reinterpret_cast<const float4*>(Ws);
#pragma unroll
  for (int j = 0; j < 8; ++j) {
    int idx = j * 256 + l * 4;
    float4 v = x4[(r * K_DIM + idx) >> 2];
#pragma unroll
    for (int p = 0; p < NPOP; ++p) {
      float4 wv = Ws4[(p * K_DIM + idx) >> 2];
      acc[p] += v.x * wv.x + v.y * wv.y + v.z * wv.z + v.w * wv.w;
    }
  }
#pragma unroll
  for (int off = 32; off > 0; off >>= 1)
#pragma unroll
    for (int p = 0; p < NPOP; ++p) acc[p] += __shfl_xor(acc[p], off, 64);

  if (l == 0) {
    float lg[NPOP];
#pragma unroll
    for (int p = 0; p < NPOP; ++p) lg[p] = acc[p] + bs[p];
    int p1 = 0;
#pragma unroll
    for (int p = 1; p < NPOP; ++p) if (lg[p] > lg[p1]) p1 = p;   // strict >: low index wins ties
    int p2 = -1;
#pragma unroll
    for (int p = 0; p < NPOP; ++p) {
      if (p == p1) continue;
      if (p2 < 0 || lg[p] > lg[p2]) p2 = p;
    }
    sel[r] = p1 * 8 + p2;
  }
}

// ---- build MERGED per-expert row lists (top1 OR top2 == ex); one block per expert ----
__global__ __launch_bounds__(256) void build_lists_kernel(const int* __restrict__ sel,
                                                          int* __restrict__ lists,
                                                          int* __restrict__ cnt) {
  const int ex = blockIdx.x;        // 0..7
  const int t  = threadIdx.x;

  __shared__ int psum[256];

  int local[32];
  int c = 0;
#pragma unroll
  for (int i = 0; i < 32; ++i) {
    int r = i * 256 + t;            // coalesced scan
    int s = sel[r];
    if ((s >> 3) == ex || (s & 7) == ex) local[c++] = r;   // top1!=top2 -> at most once
  }
  psum[t] = c;
  __syncthreads();
  for (int off = 1; off < 256; off <<= 1) {   // Hillis-Steele inclusive scan
    int v = (t >= off) ? psum[t - off] : 0;
    __syncthreads();
    psum[t] += v;
    __syncthreads();
  }
  int start = psum[t] - c;
  for (int i = 0; i < c; ++i) lists[ex * 8192 + start + i] = local[i];
  if (t == 255) cnt[ex] = psum[255];
}

// ---- gather x rows into expert-sorted packed bf16 panels (linear A for gemm) ----
// xg layout: expert g's rows at [base(g) .. base(g)+cgpad(g)), base = prefix of
// 256-aligned counts; pad rows zero-filled. Capacity 18432 rows (16384 + 8*256).
__global__ __launch_bounds__(256) void gather_x_kernel(const float* __restrict__ x,
                                                       const int* __restrict__ lists,
                                                       const int* __restrict__ cnt,
                                                       unsigned short* __restrict__ xg) {
  const int g  = blockIdx.x;        // 0..7
  const int mb = blockIdx.y;        // 0..31
  int cg = 0, base = 0;
#pragma unroll
  for (int p = 0; p < NPOP; ++p) {
    int c = cnt[p];
    if (p < g) base += (c + 255) & ~255;
    if (p == g) cg = c;
  }
  const int cgpad = (cg + 255) & ~255;
  const int r0 = mb * 256;
  if (r0 >= cgpad) return;
  const int* list = lists + g * 8192;
  const int t = threadIdx.x;        // thread t covers cols [8t, 8t+8)

  for (int i = 0; i < 256; ++i) {
    int r = r0 + i;
    uint4* dst = reinterpret_cast<uint4*>(xg + (size_t)(base + r) * K_DIM + t * 8);
    if (r < cg) {
      const float* src = x + (size_t)list[r] * K_DIM + t * 8;
      float4 v0 = *reinterpret_cast<const float4*>(src);
      float4 v1 = *reinterpret_cast<const float4*>(src + 4);
      uint4 o;
      o.x = (unsigned)f2bf(v0.x) | ((unsigned)f2bf(v0.y) << 16);
      o.y = (unsigned)f2bf(v0.z) | ((unsigned)f2bf(v0.w) << 16);
      o.z = (unsigned)f2bf(v1.x) | ((unsigned)f2bf(v1.y) << 16);
      o.w = (unsigned)f2bf(v1.z) | ((unsigned)f2bf(v1.w) << 16);
      *dst = o;
    } else {
      uint4 z = {0u, 0u, 0u, 0u};
      *dst = z;                      // deterministic pad (no NaN garbage)
    }
  }
}

// ============================================================================
// Grouped GEMM over MERGED expert lists, LINEAR pre-gathered A (xg).
// 256x256 tile, BK=64, 8 waves (2Mx4N), m201 8-phase schedule, atomic epilogue.
// Staging plan per K-tile (slot-safe):
//   p1: reads A0+B0 (12 ds)    ; no stage
//   p2: reads B1 (4 ds)        ; stage A0+B0 of kt+2 (both freed @p1)
//   p3: reads A1 (8 ds)        ; stage B1 of kt+2 (freed @p2)
//   p4: no reads               ; stage A1 of kt+2 (freed @p3); vmcnt(8)
// vmcnt(8): exactly this K-tile's 8 kt+2 loads stay in flight; kt+1 drained.
// ============================================================================

#define BAR()  asm volatile("s_barrier" ::: "memory")
#define VMW8   asm volatile("s_waitcnt vmcnt(8)" ::: "memory")
#define VMW0   asm volatile("s_waitcnt vmcnt(0)" ::: "memory")
#define SP(x)  __builtin_amdgcn_s_setprio(x)
#define SB0()  __builtin_amdgcn_sched_barrier(0)

#define STAGE_A(buf, msel, kt) do {                                            \
    unsigned short* lb_ = &As[buf][(msel) * 8192 + w * 512];                   \
    glds16((const unsigned short*)(agp + (aoff##msel##0 + (unsigned)((kt) * 128))), lb_); \
    glds16((const unsigned short*)(agp + (aoff##msel##1 + (unsigned)((kt) * 128))), lb_ + 4096); \
  } while (0)

#define STAGE_B(buf, nsel, kt) do {                                            \
    unsigned short* lb_ = &Bs[buf][(nsel) * 8192 + w * 512];                   \
    glds16((const unsigned short*)(bgp + (boff##nsel##0 + (unsigned)((kt) * 128))), lb_); \
    glds16((const unsigned short*)(bgp + (boff##nsel##1 + (unsigned)((kt) * 128))), lb_ + 4096); \
  } while (0)

#define LOAD_AF(buf, msel) do {                                                \
    const char* ab_ = (const char*)&As[0][0] + (buf) * 32768 + (msel) * 16384 + arow_rd; \
    _Pragma("unroll") for (int mi_ = 0; mi_ < 4; ++mi_) {                      \
      af[mi_][0] = *(const bf16x8*)(ab_ + mi_ * 2048 + csw0);                  \
      af[mi_][1] = *(const bf16x8*)(ab_ + mi_ * 2048 + csw1); }                \
  } while (0)

#define LOAD_BF(dst, buf, nsel) do {                                           \
    const char* bb_ = (const char*)&Bs[0][0] + (buf) * 32768 + (nsel) * 16384 + brow_rd; \
    _Pragma("unroll") for (int ni_ = 0; ni_ < 2; ++ni_) {                      \
      dst[ni_][0] = *(const bf16x8*)(bb_ + ni_ * 2048 + csw0);                 \
      dst[ni_][1] = *(const bf16x8*)(bb_ + ni_ * 2048 + csw1); }               \
  } while (0)

#define MMA(msel, nsel, bfv) do {                                              \
    _Pragma("unroll") for (int mi_ = 0; mi_ < 4; ++mi_)                        \
    _Pragma("unroll") for (int ni_ = 0; ni_ < 2; ++ni_) {                      \
      f32x4 a_ = acc[(msel)*4+mi_][(nsel)*2+ni_];                              \
      a_ = __builtin_amdgcn_mfma_f32_16x16x32_bf16(af[mi_][0], bfv[ni_][0], a_, 0, 0, 0); \
      a_ = __builtin_amdgcn_mfma_f32_16x16x32_bf16(af[mi_][1], bfv[ni_][1], a_, 0, 0, 0); \
      acc[(msel)*4+mi_][(nsel)*2+ni_] = a_; }                                  \
  } while (0)

#define HALF_ITER(buf, kt, DOS, VM) do {                                       \
    LOAD_AF(buf, 0); LOAD_BF(bf0, buf, 0);                                     \
    BAR(); SP(1); MMA(0, 0, bf0); SP(0); SB0(); BAR();                         \
    LOAD_BF(bf1, buf, 1);                                                      \
    if (DOS) { STAGE_A(buf, 0, (kt) + 2); STAGE_B(buf, 0, (kt) + 2); }         \
    BAR(); SP(1); MMA(0, 1, bf1); SP(0); SB0(); BAR();                         \
    LOAD_AF(buf, 1);                                                           \
    if (DOS) STAGE_B(buf, 1, (kt) + 2);                                        \
    BAR(); SP(1); MMA(1, 1, bf1); SP(0); SB0(); BAR();                         \
    if (DOS) STAGE_A(buf, 1, (kt) + 2);                                        \
    VM;                                                                        \
    BAR(); SP(1); MMA(1, 0, bf0); SP(0); SB0(); BAR();                         \
  } while (0)

#define EPILOGUE()                                                             \
  _Pragma("unroll") for (int mi8 = 0; mi8 < 8; ++mi8) {                        \
    const int rb = wm * 128 + ((mi8 >> 2) << 6) + ((mi8 & 3) << 4) + (quad << 2); \
    _Pragma("unroll") for (int j = 0; j < 4; ++j) {                            \
      int r = m0 + rb + j;                                                     \
      if (r < cg) {                                                            \
        int gr = list[r];                                                      \
        float* orow = out + (size_t)gr * N_DIM + n0 + wn * 64;                 \
        _Pragma("unroll") for (int nj = 0; nj < 4; ++nj) {                     \
          int col = ((nj >> 1) << 5) + ((nj & 1) << 4) + lane16;               \
          float v = 0.5f * acc[mi8][nj][j] + bv[nj];                           \
          (void)unsafeAtomicAdd(&orow[col], v);                                \
        } } } }

__global__ __launch_bounds__(512, 2) void gemm_kernel(
    const unsigned short* __restrict__ xg,
    const unsigned short* __restrict__ Wb,
    const float* __restrict__ bvec,
    const int* __restrict__ lists,
    const int* __restrict__ cnt,
    float* __restrict__ out) {
  // flat grid 2048 = 8nt x 32mt x 8g; low 3 bits = expert -> XCD = expert
  const int bid = blockIdx.x;
  const int g   = bid & 7;
  const int mt  = (bid >> 3) & 31;
  const int nt  = bid >> 8;
  int cg = 0, base = 0;
#pragma unroll
  for (int p = 0; p < NPOP; ++p) {
    int c = cnt[p];
    if (p < g) base += (c + 255) & ~255;
    if (p == g) cg = c;
  }
  const int m0 = mt * 256;
  if (m0 >= cg) return;
  const int n0 = nt * 256;

  __shared__ __align__(16) unsigned short As[2][16384];   // [buf][msel*8192 + row*64 + col]
  __shared__ __align__(16) unsigned short Bs[2][16384];

  const int t = threadIdx.x;
  const int w = t >> 6, l = t & 63;
  const int lane16 = l & 15, quad = l >> 4;
  const int wm = w >> 2, wn = w & 3;
  const int l8 = l >> 3;
  const unsigned int swS = (unsigned)(((l & 7) ^ l8) << 4);   // staging source swizzle
  const unsigned int swR = (unsigned)((l & 7) << 4);          // read swizzle (row&7 == l&7)
  const unsigned int csw0 = ((unsigned)(quad << 4)) ^ swR;            // kstep 0
  const unsigned int csw1 = ((unsigned)(64 | (quad << 4))) ^ swR;     // kstep 1
  const unsigned int arow_rd = (unsigned)(wm * 8192 + lane16 * 128);
  const unsigned int brow_rd = (unsigned)(wn * 4096 + lane16 * 128);

  const int* list = lists + g * 8192;
  const char* agp = (const char*)(xg + (size_t)(base + m0) * K_DIM);   // LINEAR A
  const char* bgp = (const char*)(Wb + (size_t)g * (N_DIM * K_DIM));

  // linear staging offsets (LDS row interleave: [0..63]=g0..63, [64..127]=g128..191,
  // [128..191]=g64..127, [192..255]=g192..255 — matches LOAD_AF/epilogue mapping)
  const int trb = w * 8 + l8;
  const unsigned int aoff00 = (unsigned)((trb)       * 4096) + swS;
  const unsigned int aoff01 = (unsigned)((128 + trb) * 4096) + swS;
  const unsigned int aoff10 = (unsigned)((64 + trb)  * 4096) + swS;
  const unsigned int aoff11 = (unsigned)((192 + trb) * 4096) + swS;
  const int rl0 = w * 8 + l8, rl1 = 64 + w * 8 + l8;
  const int b0 = n0 + ((rl0 >> 5) << 6) + (rl0 & 31);
  const int b1 = n0 + ((rl1 >> 5) << 6) + (rl1 & 31);
  const unsigned int boff00 = (unsigned)b0 * 4096u + swS;
  const unsigned int boff01 = (unsigned)b1 * 4096u + swS;
  const unsigned int boff10 = boff00 + 32u * 4096u;
  const unsigned int boff11 = boff01 + 32u * 4096u;

  bf16x8 af[4][2], bf0[2][2], bf1[2][2];
  f32x4 acc[8][4];
#pragma unroll
  for (int i = 0; i < 8; ++i)
#pragma unroll
    for (int jq = 0; jq < 4; ++jq) { f32x4 z = {0.f, 0.f, 0.f, 0.f}; acc[i][jq] = z; }

  // prologue: stage kt0 -> buf0, kt1 -> buf1 (16 loads); wait to 8 = kt0 landed
  STAGE_A(0, 0, 0); STAGE_B(0, 0, 0); STAGE_B(0, 1, 0); STAGE_A(0, 1, 0);
  STAGE_A(1, 0, 1); STAGE_B(1, 0, 1); STAGE_B(1, 1, 1); STAGE_A(1, 1, 1);
  VMW8;
  BAR();

  // 32 K-tiles of 64; each iter stages the full kt+2 (p2..p4), waits vmcnt(8) @p4
#pragma unroll 1
  for (int h = 0; h < 30; h += 2) {
    HALF_ITER(0, h,     1, VMW8);
    HALF_ITER(1, h + 1, 1, VMW8);
  }
  HALF_ITER(0, 30, 0, VMW0);
  HALF_ITER(1, 31, 0, (void)0);

  // epilogue: atomic accumulate (out zero-initialized by prep_x_sel_kernel);
  // merged list -> every selected row gets 0.5*(W x) + 0.5*b exactly once here
  const float* bias = bvec + (size_t)g * N_DIM + n0 + wn * 64;
  float bv[4];
#pragma unroll
  for (int nj = 0; nj < 4; ++nj) bv[nj] = 0.5f * bias[((nj >> 1) << 5) + ((nj & 1) << 4) + lane16];

  EPILOGUE();
}

extern "C" void kernel_launch(void* const* d_in, const int* in_sizes, int n_in,
                              void* d_out, int out_size, void* d_ws, size_t ws_size,
                              hipStream_t stream) {
  const float* x  = (const float*)d_in[0];
  const float* W  = (const float*)d_in[1];
  const float* b  = (const float*)d_in[2];
  const float* Ws = (const float*)d_in[3];
  const float* bs = (const float*)d_in[4];
  float* out = (float*)d_out;

  // ws: Wb bf16 (64MiB) | xg bf16 packed (72MiB, 18432 rows) | lists 8*8192 int
  //   | cnt 8 int | sel 8192 int   -> total ~136.4 MiB
  char* ws = (char*)d_ws;
  unsigned short* Wb = (unsigned short*)ws;
  unsigned short* xg = (unsigned short*)(ws + (size_t)67108864);
  int* lists = (int*)(ws + (size_t)67108864 + 75497472);
  int* cnt   = (int*)(ws + (size_t)67108864 + 75497472 + 262144);
  int* sel   = (int*)(ws + (size_t)67108864 + 75497472 + 262144 + 4096);

  prep_w_kernel<<<4096, 256, 0, stream>>>(W, Wb);
  prep_x_sel_kernel<<<2048, 256, 0, stream>>>(x, Ws, bs, sel, out);
  build_lists_kernel<<<8, 256, 0, stream>>>(sel, lists, cnt);
  gather_x_kernel<<<dim3(8, 32), 256, 0, stream>>>(x, lists, cnt, xg);
  gemm_kernel<<<dim3(2048), dim3(512), 0, stream>>>(xg, Wb, b, lists, cnt, out);
}

// Round 5
// 540.686 us; speedup vs baseline: 1.2182x; 1.2182x over previous
//
#include <hip/hip_runtime.h>
#include <stdint.h>

#define B_ROWS 8192
#define K_DIM 2048
#define N_DIM 2048
#define NPOP 8

typedef float f32x4 __attribute__((ext_vector_type(4)));
typedef __bf16 bf16x8 __attribute__((ext_vector_type(8)));

__device__ __forceinline__ unsigned short f2bf(float f) {
  unsigned int u = __float_as_uint(f);
  u += 0x7fffu + ((u >> 16) & 1u);   // round-to-nearest-even
  return (unsigned short)(u >> 16);
}

// async global->LDS, 16B per lane; LDS side = wave-uniform base + lane*16
__device__ __forceinline__ void glds16(const unsigned short* g, unsigned short* l) {
  __builtin_amdgcn_global_load_lds(
      (__attribute__((address_space(1))) unsigned int*)g,
      (__attribute__((address_space(3))) unsigned int*)l, 16, 0, 0);
}

// ---- W fp32 -> bf16 ----
__global__ void prep_w_kernel(const float* __restrict__ W, unsigned short* __restrict__ Wb) {
  const int n4 = NPOP * N_DIM * K_DIM / 4;
  int stride = gridDim.x * blockDim.x;
  for (int i = blockIdx.x * blockDim.x + threadIdx.x; i < n4; i += stride) {
    float4 v = reinterpret_cast<const float4*>(W)[i];
    ushort4 s;
    s.x = f2bf(v.x); s.y = f2bf(v.y); s.z = f2bf(v.z); s.w = f2bf(v.w);
    reinterpret_cast<ushort4*>(Wb)[i] = s;
  }
}

// ---- x fp32 -> bf16, selector logits, top-2 -> sel[row]; also zero-init out ----
__global__ void prep_x_sel_kernel(const float* __restrict__ x,
                                  const float* __restrict__ Ws,
                                  const float* __restrict__ bs,
                                  unsigned short* __restrict__ xb,
                                  int* __restrict__ sel,
                                  float* __restrict__ out) {
  // zero-init output (gemm accumulates atomically into it)
  {
    float4 z4 = {0.f, 0.f, 0.f, 0.f};
    float4* o4 = reinterpret_cast<float4*>(out);
    const int n4 = B_ROWS * N_DIM / 4;
    int stride = gridDim.x * blockDim.x;
    for (int i = blockIdx.x * blockDim.x + threadIdx.x; i < n4; i += stride) o4[i] = z4;
  }

  const int w = threadIdx.x >> 6;
  const int l = threadIdx.x & 63;
  const int r = blockIdx.x * 4 + w;   // 2048 blocks * 4 waves = 8192 rows

  float acc[NPOP];
#pragma unroll
  for (int p = 0; p < NPOP; ++p) acc[p] = 0.f;

  const float4* x4  = reinterpret_cast<const float4*>(x);
  const float4* Ws4 = reinterpret_cast<const float4*>(Ws);
#pragma unroll
  for (int j = 0; j < 8; ++j) {
    int idx = j * 256 + l * 4;
    float4 v = x4[(r * K_DIM + idx) >> 2];
    ushort4 s; s.x = f2bf(v.x); s.y = f2bf(v.y); s.z = f2bf(v.z); s.w = f2bf(v.w);
    *reinterpret_cast<ushort4*>(xb + (size_t)r * K_DIM + idx) = s;
#pragma unroll
    for (int p = 0; p < NPOP; ++p) {
      float4 wv = Ws4[(p * K_DIM + idx) >> 2];
      acc[p] += v.x * wv.x + v.y * wv.y + v.z * wv.z + v.w * wv.w;
    }
  }
#pragma unroll
  for (int off = 32; off > 0; off >>= 1)
#pragma unroll
    for (int p = 0; p < NPOP; ++p) acc[p] += __shfl_xor(acc[p], off, 64);

  if (l == 0) {
    float lg[NPOP];
#pragma unroll
    for (int p = 0; p < NPOP; ++p) lg[p] = acc[p] + bs[p];
    int p1 = 0;
#pragma unroll
    for (int p = 1; p < NPOP; ++p) if (lg[p] > lg[p1]) p1 = p;   // strict >: low index wins ties
    int p2 = -1;
#pragma unroll
    for (int p = 0; p < NPOP; ++p) {
      if (p == p1) continue;
      if (p2 < 0 || lg[p] > lg[p2]) p2 = p;
    }
    sel[r] = p1 * 8 + p2;
  }
}

// ---- build MERGED per-expert row lists (top1 OR top2 == ex); one block per expert ----
__global__ __launch_bounds__(256) void build_lists_kernel(const int* __restrict__ sel,
                                                          int* __restrict__ lists,
                                                          int* __restrict__ cnt) {
  const int ex = blockIdx.x;        // 0..7
  const int t  = threadIdx.x;

  __shared__ int psum[256];

  int local[32];
  int c = 0;
#pragma unroll
  for (int i = 0; i < 32; ++i) {
    int r = i * 256 + t;            // coalesced scan
    int s = sel[r];
    if ((s >> 3) == ex || (s & 7) == ex) local[c++] = r;   // top1!=top2 -> at most once
  }
  psum[t] = c;
  __syncthreads();
  for (int off = 1; off < 256; off <<= 1) {   // Hillis-Steele inclusive scan
    int v = (t >= off) ? psum[t - off] : 0;
    __syncthreads();
    psum[t] += v;
    __syncthreads();
  }
  int start = psum[t] - c;
  for (int i = 0; i < c; ++i) lists[ex * 8192 + start + i] = local[i];
  if (t == 255) cnt[ex] = psum[255];
}

// ============================================================================
// Grouped GEMM, merged expert lists, scatter-A staging (proven == linear-A),
// 128x128 tile, BK=64, 4 waves (2Mx2N), 64 KiB LDS -> 2 BLOCKS/CU (TLP hides
// barrier/vmcnt/epilogue stalls of the co-resident block; m114 co-scheduling).
// ~2100 fine blocks -> ~95% packing on 512 block-slots.
// Same verified 8-phase skeleton, homothetically halved:
//   p1: reads A0+B0 (8 ds)     ; no stage
//   p2: reads B1 (4 ds)        ; stage A0+B0 of kt+2 (chunks {0,2}, freed @p1)
//   p3: reads A1 (4 ds)        ; stage B1 of kt+2 (chunks {1,3} of B, freed @p2)
//   p4: no reads               ; stage A1 of kt+2 (freed @p3); vmcnt(8)
// 8 glds/K-tile -> vmcnt(8) leaves exactly kt+2 in flight, kt+1 drained.
// Chunk map (32-row units): A/B chunk c covers rows c*32..c*32+31;
//   msel/nsel 0 -> chunks {0,2} (read by wm/wn=0,1 at 16-row frags), 1 -> {1,3}.
// Swizzle unchanged (row stride still 128B): src col ^= ((l&7)^(l>>3))<<4,
// read col ^= ((row&7)<<4).
// ============================================================================

#define BAR()  asm volatile("s_barrier" ::: "memory")
#define VMW8   asm volatile("s_waitcnt vmcnt(8)" ::: "memory")
#define VMW0   asm volatile("s_waitcnt vmcnt(0)" ::: "memory")
#define SP(x)  __builtin_amdgcn_s_setprio(x)
#define SB0()  __builtin_amdgcn_sched_barrier(0)

#define STAGE_A(buf, msel, kt) do {                                            \
    unsigned short* lb_ = &As[buf][(msel) * 2048 + w * 512];                   \
    glds16((const unsigned short*)((const char*)xb + (aoff##msel##0 + (unsigned)((kt) * 128))), lb_); \
    glds16((const unsigned short*)((const char*)xb + (aoff##msel##1 + (unsigned)((kt) * 128))), lb_ + 4096); \
  } while (0)

#define STAGE_B(buf, nsel, kt) do {                                            \
    unsigned short* lb_ = &Bs[buf][(nsel) * 2048 + w * 512];                   \
    glds16((const unsigned short*)(bgp + (boff##nsel##0 + (unsigned)((kt) * 128))), lb_); \
    glds16((const unsigned short*)(bgp + (boff##nsel##1 + (unsigned)((kt) * 128))), lb_ + 4096); \
  } while (0)

#define LOAD_AF(buf, msel) do {                                                \
    const char* ab_ = (const char*)&As[0][0] + (buf) * 16384 + (msel) * 4096 + arow_rd; \
    _Pragma("unroll") for (int mi_ = 0; mi_ < 2; ++mi_) {                      \
      af[mi_][0] = *(const bf16x8*)(ab_ + mi_ * 2048 + csw0);                  \
      af[mi_][1] = *(const bf16x8*)(ab_ + mi_ * 2048 + csw1); }                \
  } while (0)

#define LOAD_BF(dst, buf, nsel) do {                                           \
    const char* bb_ = (const char*)&Bs[0][0] + (buf) * 16384 + (nsel) * 4096 + brow_rd; \
    _Pragma("unroll") for (int ni_ = 0; ni_ < 2; ++ni_) {                      \
      dst[ni_][0] = *(const bf16x8*)(bb_ + ni_ * 2048 + csw0);                 \
      dst[ni_][1] = *(const bf16x8*)(bb_ + ni_ * 2048 + csw1); }               \
  } while (0)

#define MMA(msel, nsel, bfv) do {                                              \
    _Pragma("unroll") for (int mi_ = 0; mi_ < 2; ++mi_)                        \
    _Pragma("unroll") for (int ni_ = 0; ni_ < 2; ++ni_) {                      \
      f32x4 a_ = acc[(msel)*2+mi_][(nsel)*2+ni_];                              \
      a_ = __builtin_amdgcn_mfma_f32_16x16x32_bf16(af[mi_][0], bfv[ni_][0], a_, 0, 0, 0); \
      a_ = __builtin_amdgcn_mfma_f32_16x16x32_bf16(af[mi_][1], bfv[ni_][1], a_, 0, 0, 0); \
      acc[(msel)*2+mi_][(nsel)*2+ni_] = a_; }                                  \
  } while (0)

#define HALF_ITER(buf, kt, DOS, VM) do {                                       \
    LOAD_AF(buf, 0); LOAD_BF(bf0, buf, 0);                                     \
    BAR(); SP(1); MMA(0, 0, bf0); SP(0); SB0(); BAR();                         \
    LOAD_BF(bf1, buf, 1);                                                      \
    if (DOS) { STAGE_A(buf, 0, (kt) + 2); STAGE_B(buf, 0, (kt) + 2); }         \
    BAR(); SP(1); MMA(0, 1, bf1); SP(0); SB0(); BAR();                         \
    LOAD_AF(buf, 1);                                                           \
    if (DOS) STAGE_B(buf, 1, (kt) + 2);                                        \
    BAR(); SP(1); MMA(1, 1, bf1); SP(0); SB0(); BAR();                         \
    if (DOS) STAGE_A(buf, 1, (kt) + 2);                                        \
    VM;                                                                        \
    BAR(); SP(1); MMA(1, 0, bf0); SP(0); SB0(); BAR();                         \
  } while (0)

#define EPILOGUE()                                                             \
  _Pragma("unroll") for (int a = 0; a < 4; ++a) {                              \
    _Pragma("unroll") for (int j = 0; j < 4; ++j) {                            \
      int r = m0 + wm * 64 + a * 16 + (quad << 2) + j;                         \
      if (r < cg) {                                                            \
        int gr = list[r];                                                      \
        float* orow = out + (size_t)gr * N_DIM + n0 + wn * 64;                 \
        _Pragma("unroll") for (int bq = 0; bq < 4; ++bq) {                     \
          int col = bq * 16 + lane16;                                          \
          float v = 0.5f * acc[a][bq][j] + bv[bq];                             \
          (void)unsafeAtomicAdd(&orow[col], v);                                \
        } } } }

__global__ __launch_bounds__(256, 2) void gemm_kernel(
    const unsigned short* __restrict__ xb,
    const unsigned short* __restrict__ Wb,
    const float* __restrict__ bvec,
    const int* __restrict__ lists,
    const int* __restrict__ cnt,
    float* __restrict__ out) {
  // flat grid 8192 = 16nt x 64mt x 8g; low 3 bits = expert -> XCD = expert.
  // nt-major per XCD: active 512KB B-panel stays hot in the XCD's L2.
  const int bid = blockIdx.x;
  const int g   = bid & 7;
  const int mt  = (bid >> 3) & 63;
  const int nt  = bid >> 9;
  const int cg  = cnt[g];
  const int m0  = mt * 128;
  if (m0 >= cg) return;                 // dead blocks exit (merged cg ~2048 avg)
  const int n0 = nt * 128;

  __shared__ __align__(16) unsigned short As[2][8192];   // [buf][row*64 + col], 128 rows
  __shared__ __align__(16) unsigned short Bs[2][8192];   // 64 KiB total -> 2 blocks/CU

  const int t = threadIdx.x;
  const int w = t >> 6, l = t & 63;     // 4 waves
  const int lane16 = l & 15, quad = l >> 4;
  const int wm = w >> 1, wn = w & 1;    // 2x2 wave grid, 64x64 per wave
  const int l8 = l >> 3;
  const unsigned int swS = (unsigned)(((l & 7) ^ l8) << 4);   // staging source swizzle
  const unsigned int swR = (unsigned)((l & 7) << 4);          // read swizzle (row&7 == l&7)
  const unsigned int csw0 = ((unsigned)(quad << 4)) ^ swR;            // kstep 0
  const unsigned int csw1 = ((unsigned)(64 | (quad << 4))) ^ swR;     // kstep 1
  const unsigned int arow_rd = (unsigned)(wm * 8192 + lane16 * 128);
  const unsigned int brow_rd = (unsigned)(wn * 8192 + lane16 * 128);

  const int* list = lists + g * 8192;
  const char* bgp = (const char*)(Wb + (size_t)g * (N_DIM * K_DIM));

  // per-thread staging sources; A scattered via list (chunk c rows = m0+c*32+trb)
  const int trb = w * 8 + l8;           // 0..31
  int r00 = m0 + trb;       int g00 = (r00 < cg) ? list[r00] : 0;  // chunk 0 (msel0,sub0)
  int r01 = m0 + 64 + trb;  int g01 = (r01 < cg) ? list[r01] : 0;  // chunk 2 (msel0,sub1)
  int r10 = m0 + 32 + trb;  int g10 = (r10 < cg) ? list[r10] : 0;  // chunk 1 (msel1,sub0)
  int r11 = m0 + 96 + trb;  int g11 = (r11 < cg) ? list[r11] : 0;  // chunk 3 (msel1,sub1)
  const unsigned int aoff00 = (unsigned)g00 * 4096u + swS;
  const unsigned int aoff01 = (unsigned)g01 * 4096u + swS;
  const unsigned int aoff10 = (unsigned)g10 * 4096u + swS;
  const unsigned int aoff11 = (unsigned)g11 * 4096u + swS;
  const unsigned int boff00 = (unsigned)(n0 + trb)      * 4096u + swS;
  const unsigned int boff01 = (unsigned)(n0 + 64 + trb) * 4096u + swS;
  const unsigned int boff10 = (unsigned)(n0 + 32 + trb) * 4096u + swS;
  const unsigned int boff11 = (unsigned)(n0 + 96 + trb) * 4096u + swS;

  bf16x8 af[2][2], bf0[2][2], bf1[2][2];
  f32x4 acc[4][4];
#pragma unroll
  for (int i = 0; i < 4; ++i)
#pragma unroll
    for (int jq = 0; jq < 4; ++jq) { f32x4 z = {0.f, 0.f, 0.f, 0.f}; acc[i][jq] = z; }

  // prologue: stage kt0 -> buf0 (8 loads), kt1 -> buf1 (8); wait to 8 = kt0 landed
  STAGE_A(0, 0, 0); STAGE_B(0, 0, 0); STAGE_B(0, 1, 0); STAGE_A(0, 1, 0);
  STAGE_A(1, 0, 1); STAGE_B(1, 0, 1); STAGE_B(1, 1, 1); STAGE_A(1, 1, 1);
  VMW8;
  BAR();

  // 32 K-tiles of 64; each iter stages the full kt+2 (p2..p4), waits vmcnt(8) @p4
#pragma unroll 1
  for (int h = 0; h < 30; h += 2) {
    HALF_ITER(0, h,     1, VMW8);
    HALF_ITER(1, h + 1, 1, VMW8);
  }
  HALF_ITER(0, 30, 0, VMW0);
  HALF_ITER(1, 31, 0, (void)0);

  // epilogue: atomic accumulate (out zero-initialized by prep_x_sel_kernel);
  // merged list -> every selected row gets 0.5*(W x) + 0.5*b exactly once here
  const float* bias = bvec + (size_t)g * N_DIM + n0 + wn * 64;
  float bv[4];
#pragma unroll
  for (int bq = 0; bq < 4; ++bq) bv[bq] = 0.5f * bias[bq * 16 + lane16];

  EPILOGUE();
}

extern "C" void kernel_launch(void* const* d_in, const int* in_sizes, int n_in,
                              void* d_out, int out_size, void* d_ws, size_t ws_size,
                              hipStream_t stream) {
  const float* x  = (const float*)d_in[0];
  const float* W  = (const float*)d_in[1];
  const float* b  = (const float*)d_in[2];
  const float* Ws = (const float*)d_in[3];
  const float* bs = (const float*)d_in[4];
  float* out = (float*)d_out;

  // ws: Wb bf16 (64MiB) | xb bf16 (32MiB) | lists 8*8192 int (256KiB) | cnt | sel
  char* ws = (char*)d_ws;
  unsigned short* Wb = (unsigned short*)ws;
  unsigned short* xb = (unsigned short*)(ws + (size_t)67108864);
  int* lists = (int*)(ws + (size_t)67108864 + 33554432);
  int* cnt   = (int*)(ws + (size_t)67108864 + 33554432 + 262144);
  int* sel   = (int*)(ws + (size_t)67108864 + 33554432 + 262144 + 4096);

  prep_w_kernel<<<4096, 256, 0, stream>>>(W, Wb);
  prep_x_sel_kernel<<<2048, 256, 0, stream>>>(x, Ws, bs, xb, sel, out);
  build_lists_kernel<<<8, 256, 0, stream>>>(sel, lists, cnt);
  gemm_kernel<<<dim3(8192), dim3(256), 0, stream>>>(xb, Wb, b, lists, cnt, out);
}

// Round 6
// 511.299 us; speedup vs baseline: 1.2882x; 1.0575x over previous
//
#include <hip/hip_runtime.h>
#include <stdint.h>

#define B_ROWS 8192
#define K_DIM 2048
#define N_DIM 2048
#define NPOP 8

typedef float f32x4 __attribute__((ext_vector_type(4)));
typedef __bf16 bf16x8 __attribute__((ext_vector_type(8)));

__device__ __forceinline__ unsigned short f2bf(float f) {
  unsigned int u = __float_as_uint(f);
  u += 0x7fffu + ((u >> 16) & 1u);   // round-to-nearest-even
  return (unsigned short)(u >> 16);
}

// async global->LDS, 16B per lane; LDS side = wave-uniform base + lane*16
__device__ __forceinline__ void glds16(const unsigned short* g, unsigned short* l) {
  __builtin_amdgcn_global_load_lds(
      (__attribute__((address_space(1))) unsigned int*)g,
      (__attribute__((address_space(3))) unsigned int*)l, 16, 0, 0);
}

// ============================================================================
// FUSED prep: W fp32->bf16 (320MB), out zero-init (64MB), x fp32->bf16 +
// selector top-2 (96MB) — all independent streams, one kernel, grid-stride.
// Replaces 3 serialized under-occupied kernels + 2 launch gaps.
// ============================================================================
__global__ __launch_bounds__(256) void prep_all_kernel(
    const float* __restrict__ x,
    const float* __restrict__ W,
    const float* __restrict__ Ws,
    const float* __restrict__ bs,
    unsigned short* __restrict__ xb,
    unsigned short* __restrict__ Wb,
    int* __restrict__ sel,
    float* __restrict__ out) {
  const int tid  = blockIdx.x * 256 + threadIdx.x;
  const int nthr = gridDim.x * 256;

  // ---- W fp32 -> bf16 ----
  {
    const int n4 = NPOP * N_DIM * K_DIM / 4;
    for (int i = tid; i < n4; i += nthr) {
      float4 v = reinterpret_cast<const float4*>(W)[i];
      ushort4 s;
      s.x = f2bf(v.x); s.y = f2bf(v.y); s.z = f2bf(v.z); s.w = f2bf(v.w);
      reinterpret_cast<ushort4*>(Wb)[i] = s;
    }
  }
  // ---- zero-init output (gemm accumulates atomically into it) ----
  {
    float4 z4 = {0.f, 0.f, 0.f, 0.f};
    float4* o4 = reinterpret_cast<float4*>(out);
    const int n4 = B_ROWS * N_DIM / 4;
    for (int i = tid; i < n4; i += nthr) o4[i] = z4;
  }

  // ---- x fp32 -> bf16 + selector logits + top-2 (first 2048 blocks) ----
  if (blockIdx.x >= 2048) return;
  const int w = threadIdx.x >> 6;
  const int l = threadIdx.x & 63;
  const int r = blockIdx.x * 4 + w;   // 2048 blocks * 4 waves = 8192 rows

  float acc[NPOP];
#pragma unroll
  for (int p = 0; p < NPOP; ++p) acc[p] = 0.f;

  const float4* x4  = reinterpret_cast<const float4*>(x);
  const float4* Ws4 = reinterpret_cast<const float4*>(Ws);
#pragma unroll
  for (int j = 0; j < 8; ++j) {
    int idx = j * 256 + l * 4;
    float4 v = x4[(r * K_DIM + idx) >> 2];
    ushort4 s; s.x = f2bf(v.x); s.y = f2bf(v.y); s.z = f2bf(v.z); s.w = f2bf(v.w);
    *reinterpret_cast<ushort4*>(xb + (size_t)r * K_DIM + idx) = s;
#pragma unroll
    for (int p = 0; p < NPOP; ++p) {
      float4 wv = Ws4[(p * K_DIM + idx) >> 2];
      acc[p] += v.x * wv.x + v.y * wv.y + v.z * wv.z + v.w * wv.w;
    }
  }
#pragma unroll
  for (int off = 32; off > 0; off >>= 1)
#pragma unroll
    for (int p = 0; p < NPOP; ++p) acc[p] += __shfl_xor(acc[p], off, 64);

  if (l == 0) {
    float lg[NPOP];
#pragma unroll
    for (int p = 0; p < NPOP; ++p) lg[p] = acc[p] + bs[p];
    int p1 = 0;
#pragma unroll
    for (int p = 1; p < NPOP; ++p) if (lg[p] > lg[p1]) p1 = p;   // strict >: low index wins ties
    int p2 = -1;
#pragma unroll
    for (int p = 0; p < NPOP; ++p) {
      if (p == p1) continue;
      if (p2 < 0 || lg[p] > lg[p2]) p2 = p;
    }
    sel[r] = p1 * 8 + p2;
  }
}

// ---- build MERGED per-expert row lists (top1 OR top2 == ex); one block per expert ----
__global__ __launch_bounds__(256) void build_lists_kernel(const int* __restrict__ sel,
                                                          int* __restrict__ lists,
                                                          int* __restrict__ cnt) {
  const int ex = blockIdx.x;        // 0..7
  const int t  = threadIdx.x;

  __shared__ int psum[256];

  int local[32];
  int c = 0;
#pragma unroll
  for (int i = 0; i < 32; ++i) {
    int r = i * 256 + t;            // coalesced scan
    int s = sel[r];
    if ((s >> 3) == ex || (s & 7) == ex) local[c++] = r;   // top1!=top2 -> at most once
  }
  psum[t] = c;
  __syncthreads();
  for (int off = 1; off < 256; off <<= 1) {   // Hillis-Steele inclusive scan
    int v = (t >= off) ? psum[t - off] : 0;
    __syncthreads();
    psum[t] += v;
    __syncthreads();
  }
  int start = psum[t] - c;
  for (int i = 0; i < c; ++i) lists[ex * 8192 + start + i] = local[i];
  if (t == 255) cnt[ex] = psum[255];
}

// ============================================================================
// Grouped GEMM, 128x128 tile, BK=64, 4 waves, 64 KiB LDS -> 2 blocks/CU.
// 2-PHASE per K-tile (16 MFMA per cluster — m201's MFMA:overhead ratio),
// 4 barriers/K-tile (was 8). Counted vmcnt, XOR swizzle unchanged.
//
// Staging plan (slot-safe, depth-2), per half-iter H(buf,kt):
//   p1: reads A0,B0,B1 of buf (12 ds); stage A1(buf^1)@kt+1   [DOS1]
//       (A1 of buf^1 was read at prev half-iter p2, barrier-separated)
//   -- BAR / 16 MFMA (m0n0+m0n1) / BAR --
//   p2: reads A1 of buf (4 ds); stage A0,B0,B1(buf)@kt+2      [DOS2]
//       (those regions read @p1, barrier-separated); vmcnt(6)
//   -- BAR / 16 MFMA (m1n1+m1n0) / BAR --
// vmcnt(6) proof: outstanding at VMW = [p2's 6]+[p1's 2]+older; drain-to-6
// completes p1's A1(buf^1)@kt+1 (read next half-iter p2) and everything
// older incl. A0B0B1(buf^1)@kt+1 staged last half-iter (read next p1).
// Prologue: 8 (buf0@0 full) + 6 (buf1@1 A0,B0,B1) = 14 loads, vmcnt(6)
// drains buf0@0; A1(buf1)@1 staged at H(0,0) p1 per steady state.
// ============================================================================

#define BAR()  asm volatile("s_barrier" ::: "memory")
#define VMW6   asm volatile("s_waitcnt vmcnt(6)" ::: "memory")
#define VMW0   asm volatile("s_waitcnt vmcnt(0)" ::: "memory")
#define SP(x)  __builtin_amdgcn_s_setprio(x)
#define SB0()  __builtin_amdgcn_sched_barrier(0)

#define STAGE_A(buf, msel, kt) do {                                            \
    unsigned short* lb_ = &As[buf][(msel) * 2048 + w * 512];                   \
    glds16((const unsigned short*)((const char*)xb + (aoff##msel##0 + (unsigned)((kt) * 128))), lb_); \
    glds16((const unsigned short*)((const char*)xb + (aoff##msel##1 + (unsigned)((kt) * 128))), lb_ + 4096); \
  } while (0)

#define STAGE_B(buf, nsel, kt) do {                                            \
    unsigned short* lb_ = &Bs[buf][(nsel) * 2048 + w * 512];                   \
    glds16((const unsigned short*)(bgp + (boff##nsel##0 + (unsigned)((kt) * 128))), lb_); \
    glds16((const unsigned short*)(bgp + (boff##nsel##1 + (unsigned)((kt) * 128))), lb_ + 4096); \
  } while (0)

#define LOAD_AF(buf, msel) do {                                                \
    const char* ab_ = (const char*)&As[0][0] + (buf) * 16384 + (msel) * 4096 + arow_rd; \
    _Pragma("unroll") for (int mi_ = 0; mi_ < 2; ++mi_) {                      \
      af[mi_][0] = *(const bf16x8*)(ab_ + mi_ * 2048 + csw0);                  \
      af[mi_][1] = *(const bf16x8*)(ab_ + mi_ * 2048 + csw1); }                \
  } while (0)

#define LOAD_BF(dst, buf, nsel) do {                                           \
    const char* bb_ = (const char*)&Bs[0][0] + (buf) * 16384 + (nsel) * 4096 + brow_rd; \
    _Pragma("unroll") for (int ni_ = 0; ni_ < 2; ++ni_) {                      \
      dst[ni_][0] = *(const bf16x8*)(bb_ + ni_ * 2048 + csw0);                 \
      dst[ni_][1] = *(const bf16x8*)(bb_ + ni_ * 2048 + csw1); }               \
  } while (0)

#define MMA(msel, nsel, bfv) do {                                              \
    _Pragma("unroll") for (int mi_ = 0; mi_ < 2; ++mi_)                        \
    _Pragma("unroll") for (int ni_ = 0; ni_ < 2; ++ni_) {                      \
      f32x4 a_ = acc[(msel)*2+mi_][(nsel)*2+ni_];                              \
      a_ = __builtin_amdgcn_mfma_f32_16x16x32_bf16(af[mi_][0], bfv[ni_][0], a_, 0, 0, 0); \
      a_ = __builtin_amdgcn_mfma_f32_16x16x32_bf16(af[mi_][1], bfv[ni_][1], a_, 0, 0, 0); \
      acc[(msel)*2+mi_][(nsel)*2+ni_] = a_; }                                  \
  } while (0)

#define HALF_ITER(buf, kt, DOS1, DOS2, VM) do {                                \
    LOAD_AF(buf, 0); LOAD_BF(bf0, buf, 0); LOAD_BF(bf1, buf, 1);               \
    if (DOS1) STAGE_A((buf) ^ 1, 1, (kt) + 1);                                 \
    BAR(); SP(1); MMA(0, 0, bf0); MMA(0, 1, bf1); SP(0); SB0(); BAR();         \
    LOAD_AF(buf, 1);                                                           \
    if (DOS2) { STAGE_A(buf, 0, (kt) + 2); STAGE_B(buf, 0, (kt) + 2);          \
                STAGE_B(buf, 1, (kt) + 2); }                                   \
    VM;                                                                        \
    BAR(); SP(1); MMA(1, 1, bf1); MMA(1, 0, bf0); SP(0); SB0(); BAR();         \
  } while (0)

#define EPILOGUE()                                                             \
  _Pragma("unroll") for (int a = 0; a < 4; ++a) {                              \
    _Pragma("unroll") for (int j = 0; j < 4; ++j) {                            \
      int r = m0 + wm * 64 + a * 16 + (quad << 2) + j;                         \
      if (r < cg) {                                                            \
        int gr = list[r];                                                      \
        float* orow = out + (size_t)gr * N_DIM + n0 + wn * 64;                 \
        _Pragma("unroll") for (int bq = 0; bq < 4; ++bq) {                     \
          int col = bq * 16 + lane16;                                          \
          float v = 0.5f * acc[a][bq][j] + bv[bq];                             \
          (void)unsafeAtomicAdd(&orow[col], v);                                \
        } } } }

__global__ __launch_bounds__(256, 2) void gemm_kernel(
    const unsigned short* __restrict__ xb,
    const unsigned short* __restrict__ Wb,
    const float* __restrict__ bvec,
    const int* __restrict__ lists,
    const int* __restrict__ cnt,
    float* __restrict__ out) {
  // flat grid 8192 = 16nt x 64mt x 8g; low 3 bits = expert -> XCD = expert.
  const int bid = blockIdx.x;
  const int g   = bid & 7;
  const int mt  = (bid >> 3) & 63;
  const int nt  = bid >> 9;
  const int cg  = cnt[g];
  const int m0  = mt * 128;
  if (m0 >= cg) return;                 // dead blocks exit (merged cg ~2048 avg)
  const int n0 = nt * 128;

  __shared__ __align__(16) unsigned short As[2][8192];   // [buf][row*64 + col], 128 rows
  __shared__ __align__(16) unsigned short Bs[2][8192];   // 64 KiB total -> 2 blocks/CU

  const int t = threadIdx.x;
  const int w = t >> 6, l = t & 63;     // 4 waves
  const int lane16 = l & 15, quad = l >> 4;
  const int wm = w >> 1, wn = w & 1;    // 2x2 wave grid, 64x64 per wave
  const int l8 = l >> 3;
  const unsigned int swS = (unsigned)(((l & 7) ^ l8) << 4);   // staging source swizzle
  const unsigned int swR = (unsigned)((l & 7) << 4);          // read swizzle (row&7 == l&7)
  const unsigned int csw0 = ((unsigned)(quad << 4)) ^ swR;            // kstep 0
  const unsigned int csw1 = ((unsigned)(64 | (quad << 4))) ^ swR;     // kstep 1
  const unsigned int arow_rd = (unsigned)(wm * 8192 + lane16 * 128);
  const unsigned int brow_rd = (unsigned)(wn * 8192 + lane16 * 128);

  const int* list = lists + g * 8192;
  const char* bgp = (const char*)(Wb + (size_t)g * (N_DIM * K_DIM));

  // per-thread staging sources; A scattered via list (chunk c rows = m0+c*32+trb)
  const int trb = w * 8 + l8;           // 0..31
  int r00 = m0 + trb;       int g00 = (r00 < cg) ? list[r00] : 0;  // chunk 0 (msel0,sub0)
  int r01 = m0 + 64 + trb;  int g01 = (r01 < cg) ? list[r01] : 0;  // chunk 2 (msel0,sub1)
  int r10 = m0 + 32 + trb;  int g10 = (r10 < cg) ? list[r10] : 0;  // chunk 1 (msel1,sub0)
  int r11 = m0 + 96 + trb;  int g11 = (r11 < cg) ? list[r11] : 0;  // chunk 3 (msel1,sub1)
  const unsigned int aoff00 = (unsigned)g00 * 4096u + swS;
  const unsigned int aoff01 = (unsigned)g01 * 4096u + swS;
  const unsigned int aoff10 = (unsigned)g10 * 4096u + swS;
  const unsigned int aoff11 = (unsigned)g11 * 4096u + swS;
  const unsigned int boff00 = (unsigned)(n0 + trb)      * 4096u + swS;
  const unsigned int boff01 = (unsigned)(n0 + 64 + trb) * 4096u + swS;
  const unsigned int boff10 = (unsigned)(n0 + 32 + trb) * 4096u + swS;
  const unsigned int boff11 = (unsigned)(n0 + 96 + trb) * 4096u + swS;

  bf16x8 af[2][2], bf0[2][2], bf1[2][2];
  f32x4 acc[4][4];
#pragma unroll
  for (int i = 0; i < 4; ++i)
#pragma unroll
    for (int jq = 0; jq < 4; ++jq) { f32x4 z = {0.f, 0.f, 0.f, 0.f}; acc[i][jq] = z; }

  // prologue: buf0@kt0 full (8) + buf1@kt1 {A0,B0,B1} (6); vmcnt(6) = kt0 landed.
  // A1(buf1)@kt1 staged at H(0,0) p1 (steady-state DOS1).
  STAGE_A(0, 0, 0); STAGE_B(0, 0, 0); STAGE_B(0, 1, 0); STAGE_A(0, 1, 0);
  STAGE_A(1, 0, 1); STAGE_B(1, 0, 1); STAGE_B(1, 1, 1);
  VMW6;
  BAR();

  // 32 K-tiles of 64
#pragma unroll 1
  for (int h = 0; h < 30; h += 2) {
    HALF_ITER(0, h,     1, 1, VMW6);
    HALF_ITER(1, h + 1, 1, 1, VMW6);
  }
  HALF_ITER(0, 30, 1, 0, VMW0);
  HALF_ITER(1, 31, 0, 0, (void)0);

  // epilogue: atomic accumulate (out zero-initialized by prep_all_kernel);
  // merged list -> every selected row gets 0.5*(W x) + 0.5*b exactly once here
  const float* bias = bvec + (size_t)g * N_DIM + n0 + wn * 64;
  float bv[4];
#pragma unroll
  for (int bq = 0; bq < 4; ++bq) bv[bq] = 0.5f * bias[bq * 16 + lane16];

  EPILOGUE();
}

extern "C" void kernel_launch(void* const* d_in, const int* in_sizes, int n_in,
                              void* d_out, int out_size, void* d_ws, size_t ws_size,
                              hipStream_t stream) {
  const float* x  = (const float*)d_in[0];
  const float* W  = (const float*)d_in[1];
  const float* b  = (const float*)d_in[2];
  const float* Ws = (const float*)d_in[3];
  const float* bs = (const float*)d_in[4];
  float* out = (float*)d_out;

  // ws: Wb bf16 (64MiB) | xb bf16 (32MiB) | lists 8*8192 int (256KiB) | cnt | sel
  char* ws = (char*)d_ws;
  unsigned short* Wb = (unsigned short*)ws;
  unsigned short* xb = (unsigned short*)(ws + (size_t)67108864);
  int* lists = (int*)(ws + (size_t)67108864 + 33554432);
  int* cnt   = (int*)(ws + (size_t)67108864 + 33554432 + 262144);
  int* sel   = (int*)(ws + (size_t)67108864 + 33554432 + 262144 + 4096);

  prep_all_kernel<<<4096, 256, 0, stream>>>(x, W, Ws, bs, xb, Wb, sel, out);
  build_lists_kernel<<<8, 256, 0, stream>>>(sel, lists, cnt);
  gemm_kernel<<<dim3(8192), dim3(256), 0, stream>>>(xb, Wb, b, lists, cnt, out);
}